// Round 1
// baseline (1139.759 us; speedup 1.0000x reference)
//
#include <hip/hip_runtime.h>
#include <hip/hip_bf16.h>
#include <math.h>

#define B 8
#define T 448
#define D 1024
#define H 16
#define DH 64
#define M (B*T)

#define BM 64
#define BN 64
#define BK 16

// ---------------- fp32 tiled GEMM: C[M,N] = A[M,K] @ W[K,N] (+ bias) ----------------
__global__ __launch_bounds__(256) void sgemm_bias(
    const float* __restrict__ A, const float* __restrict__ W,
    const float* __restrict__ bias, float* __restrict__ C,
    int K, int N)
{
    __shared__ float As[BK][BM];   // As[k][m]
    __shared__ float Bs[BK][BN];   // Bs[k][n]
    const int bm = blockIdx.y * BM;
    const int bn = blockIdx.x * BN;
    const int tid = threadIdx.x;
    const int tx = tid & 15;       // n-tile coord
    const int ty = tid >> 4;       // m-tile coord

    const int ar = tid >> 2;             // 0..63  A row within tile
    const int ac = (tid & 3) << 2;       // 0,4,8,12  A col (k) within tile
    const int wr = tid >> 4;             // 0..15  W row (k) within tile
    const int wc = (tid & 15) << 2;      // 0..60  W col within tile

    float acc[4][4] = {};

    for (int k0 = 0; k0 < K; k0 += BK) {
        float4 a4 = *(const float4*)(A + (size_t)(bm + ar) * K + k0 + ac);
        float4 b4 = *(const float4*)(W + (size_t)(k0 + wr) * N + bn + wc);
        __syncthreads();   // protect previous iteration's reads
        As[ac + 0][ar] = a4.x;
        As[ac + 1][ar] = a4.y;
        As[ac + 2][ar] = a4.z;
        As[ac + 3][ar] = a4.w;
        *(float4*)&Bs[wr][wc] = b4;
        __syncthreads();

        #pragma unroll
        for (int k = 0; k < BK; ++k) {
            float a[4], b[4];
            #pragma unroll
            for (int i = 0; i < 4; ++i) a[i] = As[k][(ty << 2) + i];
            #pragma unroll
            for (int j = 0; j < 4; ++j) b[j] = Bs[k][(tx << 2) + j];
            #pragma unroll
            for (int i = 0; i < 4; ++i)
                #pragma unroll
                for (int j = 0; j < 4; ++j)
                    acc[i][j] = fmaf(a[i], b[j], acc[i][j]);
        }
    }

    float bb[4] = {0.f, 0.f, 0.f, 0.f};
    if (bias) {
        #pragma unroll
        for (int j = 0; j < 4; ++j) bb[j] = bias[bn + (tx << 2) + j];
    }
    #pragma unroll
    for (int i = 0; i < 4; ++i) {
        const int row = bm + (ty << 2) + i;
        float4 o;
        o.x = acc[i][0] + bb[0];
        o.y = acc[i][1] + bb[1];
        o.z = acc[i][2] + bb[2];
        o.w = acc[i][3] + bb[3];
        *(float4*)(C + (size_t)row * N + bn + (tx << 2)) = o;
    }
}

// ---------------- attention: one wave per (b,h,t) query row ----------------
// Q: [B,T,D] unscaled (x@Wq+bq); Kc,Vc: [B,T,D]; O: [B,T,D]
// score = (q . k) * dh^-0.5 = dot * 0.125, causal (k <= t)
__global__ __launch_bounds__(256) void attn_kernel(
    const float* __restrict__ Q, const float* __restrict__ Kc,
    const float* __restrict__ Vc, float* __restrict__ O)
{
    const int wave = threadIdx.x >> 6;
    const int lane = threadIdx.x & 63;
    const int gw = blockIdx.x * 4 + wave;       // [0, B*H*T)
    const int t  = gw % T;
    const int bh = gw / T;
    const int h  = bh % H;
    const int b  = bh / H;

    __shared__ float qs[4][DH];
    __shared__ float wsm[4][T];

    qs[wave][lane] = Q[((size_t)b * T + t) * D + h * DH + lane];
    __syncthreads();

    // ---- QK^T: lane handles keys k = lane + 64*j, j in [0,7) ----
    const float* kbase = Kc + (size_t)b * T * D + h * DH;
    float sc[7];
    #pragma unroll
    for (int j = 0; j < 7; ++j) {
        const int k = lane + 64 * j;
        float dot = 0.f;
        if (k <= t) {
            const float4* kp = (const float4*)(kbase + (size_t)k * D);
            #pragma unroll
            for (int d4 = 0; d4 < 16; ++d4) {
                float4 kk = kp[d4];
                dot = fmaf(qs[wave][d4 * 4 + 0], kk.x, dot);
                dot = fmaf(qs[wave][d4 * 4 + 1], kk.y, dot);
                dot = fmaf(qs[wave][d4 * 4 + 2], kk.z, dot);
                dot = fmaf(qs[wave][d4 * 4 + 3], kk.w, dot);
            }
            sc[j] = dot * 0.125f;
        } else {
            sc[j] = -INFINITY;
        }
    }

    // ---- softmax over 448 scores (distributed 7/lane) ----
    float mx = sc[0];
    #pragma unroll
    for (int j = 1; j < 7; ++j) mx = fmaxf(mx, sc[j]);
    #pragma unroll
    for (int off = 32; off > 0; off >>= 1) mx = fmaxf(mx, __shfl_xor(mx, off, 64));

    float p[7];
    float lsum = 0.f;
    #pragma unroll
    for (int j = 0; j < 7; ++j) {
        p[j] = expf(sc[j] - mx);   // exp(-inf) == 0 for masked keys
        lsum += p[j];
    }
    #pragma unroll
    for (int off = 32; off > 0; off >>= 1) lsum += __shfl_xor(lsum, off, 64);
    const float inv = 1.f / lsum;

    #pragma unroll
    for (int j = 0; j < 7; ++j) wsm[wave][lane + 64 * j] = p[j] * inv;
    __syncthreads();

    // ---- PV: lane owns output dim d = lane; causal bound t is wave-uniform ----
    const float* vbase = Vc + (size_t)b * T * D + h * DH + lane;
    float acc = 0.f;
    #pragma unroll 4
    for (int k = 0; k <= t; ++k) {
        acc = fmaf(wsm[wave][k], vbase[(size_t)k * D], acc);
    }
    O[((size_t)b * T + t) * D + h * DH + lane] = acc;
}

extern "C" void kernel_launch(void* const* d_in, const int* in_sizes, int n_in,
                              void* d_out, int out_size, void* d_ws, size_t ws_size,
                              hipStream_t stream) {
    const float* x  = (const float*)d_in[0];
    // d_in[1]=k_cache, d_in[2]=v_cache: fully overwritten (T_new==T) -> unused
    // d_in[3]=mask: pure causal -> applied structurally
    const float* Wq = (const float*)d_in[4];
    const float* bq = (const float*)d_in[5];
    const float* Wk = (const float*)d_in[6];
    const float* Wv = (const float*)d_in[7];
    const float* bv = (const float*)d_in[8];
    const float* Wo = (const float*)d_in[9];
    const float* bo = (const float*)d_in[10];

    float* out  = (float*)d_out;                 // [M,D]
    float* kout = out + (size_t)M * D;           // k_cache output = x@Wk
    float* vout = out + 2 * (size_t)M * D;       // v_cache output = x@Wv+bv

    float* q_ws = (float*)d_ws;                  // [M,D] q projection
    float* a_ws = q_ws + (size_t)M * D;          // [M,D] attention output

    dim3 gg(D / BN, M / BM);   // (16, 56)
    sgemm_bias<<<gg, 256, 0, stream>>>(x, Wq, bq,      q_ws, D, D);
    sgemm_bias<<<gg, 256, 0, stream>>>(x, Wk, nullptr, kout, D, D);
    sgemm_bias<<<gg, 256, 0, stream>>>(x, Wv, bv,      vout, D, D);
    attn_kernel<<<B * H * T / 4, 256, 0, stream>>>(q_ws, kout, vout, a_ws);
    sgemm_bias<<<gg, 256, 0, stream>>>(a_ws, Wo, bo, out, D, D);
}

// Round 2
// 235.527 us; speedup vs baseline: 4.8392x; 4.8392x over previous
//
#include <hip/hip_runtime.h>
#include <hip/hip_bf16.h>
#include <math.h>

#define B 8
#define T 448
#define D 1024
#define H 16
#define DH 64
#define M (B*T)

typedef short short8 __attribute__((ext_vector_type(8)));
typedef float floatx4 __attribute__((ext_vector_type(4)));
typedef unsigned short u16;

// fp32 -> bf16 round-to-nearest-even (inputs finite; no NaN handling needed)
__device__ __forceinline__ u16 f2bf(float f) {
    union { float f; unsigned u; } v; v.f = f;
    unsigned r = v.u + 0x7FFF + ((v.u >> 16) & 1);
    return (u16)(r >> 16);
}

// ---------------- x fp32 -> bf16 ----------------
__global__ __launch_bounds__(256) void xconv(const float* __restrict__ x, u16* __restrict__ xb) {
    const int i = blockIdx.x * 256 + threadIdx.x;
    float4 v = ((const float4*)x)[i];
    ushort4 o;
    o.x = f2bf(v.x); o.y = f2bf(v.y); o.z = f2bf(v.z); o.w = f2bf(v.w);
    ((ushort4*)xb)[i] = o;
}

// ---------------- W[K][N] fp32 -> Wt[N][K] bf16 (64x64 LDS tile transpose) ----------------
__global__ __launch_bounds__(256) void wconv(const float* __restrict__ W, u16* __restrict__ Wt) {
    __shared__ float tile[64][65];
    const int k0 = blockIdx.y * 64, n0 = blockIdx.x * 64;
    const int tr = threadIdx.x >> 4;    // 0..15
    const int tc = threadIdx.x & 15;    // 0..15
    #pragma unroll
    for (int i = 0; i < 4; ++i) {
        float4 v = *(const float4*)(W + (size_t)(k0 + tr + 16 * i) * D + n0 + tc * 4);
        tile[tr + 16 * i][tc * 4 + 0] = v.x;
        tile[tr + 16 * i][tc * 4 + 1] = v.y;
        tile[tr + 16 * i][tc * 4 + 2] = v.z;
        tile[tr + 16 * i][tc * 4 + 3] = v.w;
    }
    __syncthreads();
    #pragma unroll
    for (int i = 0; i < 4; ++i) {
        const int n = tr + 16 * i;
        ushort4 o;
        o.x = f2bf(tile[tc * 4 + 0][n]);
        o.y = f2bf(tile[tc * 4 + 1][n]);
        o.z = f2bf(tile[tc * 4 + 2][n]);
        o.w = f2bf(tile[tc * 4 + 3][n]);
        *(ushort4*)(Wt + (size_t)(n0 + n) * D + k0 + tc * 4) = o;
    }
}

// ---------------- bf16 MFMA GEMM: C[M][1024] = A[M][1024] @ Bt[1024][1024]^T + bias ----------------
// A bf16 row-major [m][k]; Bt bf16 [n][k] (pre-transposed weight). 128x64 block tile, BK=32.
#define GBM 128
#define GBN 64
#define GBK 32
__global__ __launch_bounds__(256) void gemm_bt(
    const u16* __restrict__ A, const u16* __restrict__ Bt,
    const float* __restrict__ bias,
    float* __restrict__ Cf,   // optional fp32 out
    u16* __restrict__ Cb)     // optional bf16 out
{
    __shared__ u16 As[GBM][GBK + 8];   // pad 8 bf16 (16B): row stride 80B, 2-way banks
    __shared__ u16 Bs[GBN][GBK + 8];
    const int m0 = blockIdx.y * GBM;
    const int n0 = blockIdx.x * GBN;
    const int tid = threadIdx.x;
    const int wave = tid >> 6, lane = tid & 63;
    const int wy = wave >> 1, wx = wave & 1;      // 2x2 waves over 128x64
    const int lrow = lane & 15, lquad = lane >> 4;

    floatx4 acc[4][2];
    #pragma unroll
    for (int i = 0; i < 4; ++i)
        #pragma unroll
        for (int j = 0; j < 2; ++j)
            acc[i][j] = (floatx4){0.f, 0.f, 0.f, 0.f};

    const int sa = tid * 2;
    for (int k0 = 0; k0 < 1024; k0 += GBK) {
        // A tile: 128 rows x 32 k = 4096 bf16 -> 2 x short8 per thread
        short8 a0 = *(const short8*)(A + (size_t)(m0 + (sa >> 2)) * 1024 + k0 + (sa & 3) * 8);
        short8 a1 = *(const short8*)(A + (size_t)(m0 + ((sa + 1) >> 2)) * 1024 + k0 + ((sa + 1) & 3) * 8);
        // B tile: 64 rows x 32 k = 2048 bf16 -> 1 x short8 per thread
        short8 b0 = *(const short8*)(Bt + (size_t)(n0 + (tid >> 2)) * 1024 + k0 + (tid & 3) * 8);
        __syncthreads();   // protect previous iteration's fragment reads
        *(short8*)&As[sa >> 2][(sa & 3) * 8] = a0;
        *(short8*)&As[(sa + 1) >> 2][((sa + 1) & 3) * 8] = a1;
        *(short8*)&Bs[tid >> 2][(tid & 3) * 8] = b0;
        __syncthreads();
        short8 af[4], bfr[2];
        #pragma unroll
        for (int i = 0; i < 4; ++i)
            af[i] = *(const short8*)&As[wy * 64 + i * 16 + lrow][lquad * 8];
        #pragma unroll
        for (int j = 0; j < 2; ++j)
            bfr[j] = *(const short8*)&Bs[wx * 32 + j * 16 + lrow][lquad * 8];
        #pragma unroll
        for (int i = 0; i < 4; ++i)
            #pragma unroll
            for (int j = 0; j < 2; ++j)
                acc[i][j] = __builtin_amdgcn_mfma_f32_16x16x32_bf16(af[i], bfr[j], acc[i][j], 0, 0, 0);
    }

    #pragma unroll
    for (int j = 0; j < 2; ++j) {
        const int col = n0 + wx * 32 + j * 16 + lrow;
        const float bb = bias ? bias[col] : 0.f;
        #pragma unroll
        for (int i = 0; i < 4; ++i) {
            #pragma unroll
            for (int r = 0; r < 4; ++r) {
                const int row = m0 + wy * 64 + i * 16 + lquad * 4 + r;
                const float v = acc[i][j][r] + bb;
                if (Cf) Cf[(size_t)row * 1024 + col] = v;
                if (Cb) Cb[(size_t)row * 1024 + col] = f2bf(v);
            }
        }
    }
}

// ---------------- flash attention, bf16 MFMA ----------------
// Block: 64 queries (4 waves x 16) of one (b,h). K/V tiles of 64 keys in LDS.
// Score domain: s2 = (q.k) * 0.125 * log2(e); softmax via exp2.
__global__ __launch_bounds__(256) void flash_attn(
    const u16* __restrict__ Qb, const u16* __restrict__ Kb,
    const u16* __restrict__ Vb, u16* __restrict__ Ob)
{
    __shared__ u16 Qs[64][72];       // [q_local][d]   pad->144B stride
    __shared__ u16 Ks[64][72];       // [key_local][d]
    __shared__ u16 Vt[64][72];       // [d][key_local] (transposed)
    __shared__ u16 Pt[4][16][72];    // per-wave P round-trip [q][key]
    const int qt = blockIdx.x;       // 0..6
    const int bh = blockIdx.y;       // 0..127
    const int h = bh & (H - 1), b = bh >> 4;
    const int tid = threadIdx.x, wave = tid >> 6, lane = tid & 63;
    const int lrow = lane & 15, lquad = lane >> 4;
    const int q0 = qt * 64;

    const size_t hoff = (size_t)h * DH;
    const u16* qbase = Qb + (size_t)b * T * D + hoff;
    const u16* kbase = Kb + (size_t)b * T * D + hoff;
    const u16* vbase = Vb + (size_t)b * T * D + hoff;

    // stage Q tile (64 x 64): 512 16B segs, 2 per thread
    {
        const int s = tid * 2;
        short8 v0 = *(const short8*)(qbase + (size_t)(q0 + (s >> 3)) * D + (s & 7) * 8);
        short8 v1 = *(const short8*)(qbase + (size_t)(q0 + ((s + 1) >> 3)) * D + ((s + 1) & 7) * 8);
        *(short8*)&Qs[s >> 3][(s & 7) * 8] = v0;
        *(short8*)&Qs[(s + 1) >> 3][((s + 1) & 7) * 8] = v1;
    }
    __syncthreads();
    short8 aq0 = *(const short8*)&Qs[wave * 16 + lrow][lquad * 8];
    short8 aq1 = *(const short8*)&Qs[wave * 16 + lrow][32 + lquad * 8];

    float m_i[4], l_i[4];
    floatx4 oacc[4];
    #pragma unroll
    for (int r = 0; r < 4; ++r) { m_i[r] = -INFINITY; l_i[r] = 0.f; }
    #pragma unroll
    for (int n = 0; n < 4; ++n) oacc[n] = (floatx4){0.f, 0.f, 0.f, 0.f};

    const float SC = 0.125f * 1.44269504088896340736f;  // scale * log2(e)
    const int nkt = qt + 1;                              // causal k-tile bound

    for (int kt = 0; kt < nkt; ++kt) {
        const int k0 = kt * 64;
        {
            const int s = tid * 2;
            const int r0 = s >> 3, o0 = (s & 7) * 8;
            const int r1 = (s + 1) >> 3, o1 = ((s + 1) & 7) * 8;
            short8 kv0 = *(const short8*)(kbase + (size_t)(k0 + r0) * D + o0);
            short8 kv1 = *(const short8*)(kbase + (size_t)(k0 + r1) * D + o1);
            short8 vv0 = *(const short8*)(vbase + (size_t)(k0 + r0) * D + o0);
            short8 vv1 = *(const short8*)(vbase + (size_t)(k0 + r1) * D + o1);
            __syncthreads();   // protect previous iteration's Ks/Vt fragment reads
            *(short8*)&Ks[r0][o0] = kv0;
            *(short8*)&Ks[r1][o1] = kv1;
            #pragma unroll
            for (int j = 0; j < 8; ++j) Vt[o0 + j][r0] = (u16)vv0[j];
            #pragma unroll
            for (int j = 0; j < 8; ++j) Vt[o1 + j][r1] = (u16)vv1[j];
        }
        __syncthreads();

        // S = Q @ K^T : 4 key-subtiles of 16
        floatx4 s4[4];
        #pragma unroll
        for (int sub = 0; sub < 4; ++sub) {
            short8 bk0 = *(const short8*)&Ks[sub * 16 + lrow][lquad * 8];
            short8 bk1 = *(const short8*)&Ks[sub * 16 + lrow][32 + lquad * 8];
            floatx4 z = (floatx4){0.f, 0.f, 0.f, 0.f};
            z = __builtin_amdgcn_mfma_f32_16x16x32_bf16(aq0, bk0, z, 0, 0, 0);
            z = __builtin_amdgcn_mfma_f32_16x16x32_bf16(aq1, bk1, z, 0, 0, 0);
            s4[sub] = z;
        }

        // online softmax (per lane: 4 q-rows, cols = key sub*16+lrow)
        float p[4][4];
        #pragma unroll
        for (int r = 0; r < 4; ++r) {
            const int qg = q0 + wave * 16 + lquad * 4 + r;
            float sv[4];
            float mx = -INFINITY;
            #pragma unroll
            for (int sub = 0; sub < 4; ++sub) {
                const int kk = k0 + sub * 16 + lrow;
                float v = s4[sub][r] * SC;
                v = (kk <= qg) ? v : -INFINITY;
                sv[sub] = v;
                mx = fmaxf(mx, v);
            }
            mx = fmaxf(mx, __shfl_xor(mx, 1));
            mx = fmaxf(mx, __shfl_xor(mx, 2));
            mx = fmaxf(mx, __shfl_xor(mx, 4));
            mx = fmaxf(mx, __shfl_xor(mx, 8));
            const float mnew = fmaxf(m_i[r], mx);      // finite after kt=0 (key 0 always visible)
            const float alpha = exp2f(m_i[r] - mnew);  // exp2(-inf)=0 at kt=0
            float ls = 0.f;
            #pragma unroll
            for (int sub = 0; sub < 4; ++sub) {
                const float pv = exp2f(sv[sub] - mnew);
                p[sub][r] = pv;
                ls += pv;
            }
            ls += __shfl_xor(ls, 1);
            ls += __shfl_xor(ls, 2);
            ls += __shfl_xor(ls, 4);
            ls += __shfl_xor(ls, 8);
            l_i[r] = l_i[r] * alpha + ls;
            m_i[r] = mnew;
            #pragma unroll
            for (int n = 0; n < 4; ++n) oacc[n][r] *= alpha;
        }

        // P: C-layout -> A-layout via per-wave LDS round-trip (bf16)
        #pragma unroll
        for (int sub = 0; sub < 4; ++sub)
            #pragma unroll
            for (int r = 0; r < 4; ++r)
                Pt[wave][lquad * 4 + r][sub * 16 + lrow] = f2bf(p[sub][r]);
        __syncthreads();   // conservative: ensure cross-lane LDS visibility
        short8 ap0 = *(const short8*)&Pt[wave][lrow][lquad * 8];
        short8 ap1 = *(const short8*)&Pt[wave][lrow][32 + lquad * 8];

        // O += P @ V : 4 d-subtiles of 16
        #pragma unroll
        for (int n = 0; n < 4; ++n) {
            short8 bv0 = *(const short8*)&Vt[n * 16 + lrow][lquad * 8];
            short8 bv1 = *(const short8*)&Vt[n * 16 + lrow][32 + lquad * 8];
            oacc[n] = __builtin_amdgcn_mfma_f32_16x16x32_bf16(ap0, bv0, oacc[n], 0, 0, 0);
            oacc[n] = __builtin_amdgcn_mfma_f32_16x16x32_bf16(ap1, bv1, oacc[n], 0, 0, 0);
        }
    }

    // epilogue: normalize, write bf16
    #pragma unroll
    for (int r = 0; r < 4; ++r) {
        const float inv = 1.f / l_i[r];
        const int qg = q0 + wave * 16 + lquad * 4 + r;
        u16* orow = Ob + ((size_t)b * T + qg) * D + hoff;
        #pragma unroll
        for (int n = 0; n < 4; ++n)
            orow[n * 16 + lrow] = f2bf(oacc[n][r] * inv);
    }
}

extern "C" void kernel_launch(void* const* d_in, const int* in_sizes, int n_in,
                              void* d_out, int out_size, void* d_ws, size_t ws_size,
                              hipStream_t stream) {
    const float* x  = (const float*)d_in[0];
    // d_in[1]=k_cache, d_in[2]=v_cache fully overwritten (T_new==T); d_in[3]=mask pure causal
    const float* Wq = (const float*)d_in[4];
    const float* bq = (const float*)d_in[5];
    const float* Wk = (const float*)d_in[6];
    const float* Wv = (const float*)d_in[7];
    const float* bv = (const float*)d_in[8];
    const float* Wo = (const float*)d_in[9];
    const float* bo = (const float*)d_in[10];

    float* out  = (float*)d_out;                  // [M,D]
    float* kout = out + (size_t)M * D;            // k_cache = x@Wk
    float* vout = out + 2 * (size_t)M * D;        // v_cache = x@Wv+bv

    u16* xb  = (u16*)d_ws;                        // [M,D] bf16 x
    u16* qb  = xb  + (size_t)M * D;               // bf16 q
    u16* kb  = qb  + (size_t)M * D;               // bf16 k
    u16* vb  = kb  + (size_t)M * D;               // bf16 v
    u16* ab  = vb  + (size_t)M * D;               // bf16 attn out
    u16* wtq = ab  + (size_t)M * D;               // [D,D] bf16 W^T each
    u16* wtk = wtq + (size_t)D * D;
    u16* wtv = wtk + (size_t)D * D;
    u16* wto = wtv + (size_t)D * D;

    xconv<<<M * D / 1024, 256, 0, stream>>>(x, xb);
    dim3 wg(16, 16);
    wconv<<<wg, 256, 0, stream>>>(Wq, wtq);
    wconv<<<wg, 256, 0, stream>>>(Wk, wtk);
    wconv<<<wg, 256, 0, stream>>>(Wv, wtv);
    wconv<<<wg, 256, 0, stream>>>(Wo, wto);

    dim3 gg(D / GBN, M / GBM);   // (16, 28)
    gemm_bt<<<gg, 256, 0, stream>>>(xb, wtq, bq,      nullptr, qb);
    gemm_bt<<<gg, 256, 0, stream>>>(xb, wtk, nullptr, kout,    kb);
    gemm_bt<<<gg, 256, 0, stream>>>(xb, wtv, bv,      vout,    vb);

    flash_attn<<<dim3(7, 128), 256, 0, stream>>>(qb, kb, vb, ab);

    gemm_bt<<<gg, 256, 0, stream>>>(ab, wto, bo, out, nullptr);
}

// Round 3
// 210.309 us; speedup vs baseline: 5.4194x; 1.1199x over previous
//
#include <hip/hip_runtime.h>
#include <hip/hip_bf16.h>
#include <math.h>

#define B 8
#define T 448
#define D 1024
#define H 16
#define DH 64
#define M (B*T)

typedef short short8 __attribute__((ext_vector_type(8)));
typedef float floatx4 __attribute__((ext_vector_type(4)));
typedef unsigned short u16;

// fp32 -> bf16 round-to-nearest-even (inputs finite)
__device__ __forceinline__ u16 f2bf(float f) {
    union { float f; unsigned u; } v; v.f = f;
    unsigned r = v.u + 0x7FFF + ((v.u >> 16) & 1);
    return (u16)(r >> 16);
}

// async global->LDS, 16 B per lane, dest = wave-uniform base + lane*16
__device__ __forceinline__ void gload16(const void* gptr, void* lptr) {
    __builtin_amdgcn_global_load_lds(
        (const __attribute__((address_space(1))) void*)gptr,
        (__attribute__((address_space(3))) void*)lptr, 16, 0, 0);
}

// ---------------- x fp32 -> bf16 ----------------
__global__ __launch_bounds__(256) void xconv(const float* __restrict__ x, u16* __restrict__ xb) {
    const int i = blockIdx.x * 256 + threadIdx.x;
    float4 v = ((const float4*)x)[i];
    ushort4 o;
    o.x = f2bf(v.x); o.y = f2bf(v.y); o.z = f2bf(v.z); o.w = f2bf(v.w);
    ((ushort4*)xb)[i] = o;
}

// ---------------- 4x W[K][N] fp32 -> Wt[N][K] bf16 (z selects weight) ----------------
__global__ __launch_bounds__(256) void wconv4(
    const float* __restrict__ Wq, const float* __restrict__ Wk,
    const float* __restrict__ Wv, const float* __restrict__ Wo,
    u16* __restrict__ wt)
{
    __shared__ float tile[64][65];
    const int z = blockIdx.z;
    const float* W = (z == 0) ? Wq : (z == 1) ? Wk : (z == 2) ? Wv : Wo;
    u16* Wt = wt + (size_t)z * D * D;
    const int k0 = blockIdx.y * 64, n0 = blockIdx.x * 64;
    const int tr = threadIdx.x >> 4, tc = threadIdx.x & 15;
    #pragma unroll
    for (int i = 0; i < 4; ++i) {
        float4 v = *(const float4*)(W + (size_t)(k0 + tr + 16 * i) * D + n0 + tc * 4);
        tile[tr + 16 * i][tc * 4 + 0] = v.x;
        tile[tr + 16 * i][tc * 4 + 1] = v.y;
        tile[tr + 16 * i][tc * 4 + 2] = v.z;
        tile[tr + 16 * i][tc * 4 + 3] = v.w;
    }
    __syncthreads();
    #pragma unroll
    for (int i = 0; i < 4; ++i) {
        const int n = tr + 16 * i;
        ushort4 o;
        o.x = f2bf(tile[tc * 4 + 0][n]);
        o.y = f2bf(tile[tc * 4 + 1][n]);
        o.z = f2bf(tile[tc * 4 + 2][n]);
        o.w = f2bf(tile[tc * 4 + 3][n]);
        *(ushort4*)(Wt + (size_t)(n0 + n) * D + k0 + tc * 4) = o;
    }
}

// ---------------- m97-structure bf16 MFMA GEMM, 128x128 tile, BK=32 ----------------
// A[M'][1024] bf16 row-major; Bt[N][1024] bf16 (weight^T).
// mode 0: fused QKV (N=3072): writes qkvb bf16 [M][3072] (q,k sections),
//         kout/vout fp32, V also transposed bf16 into vbT [B*H][64][448].
// mode 1: output proj (N=1024): writes outp fp32 + bo.
__global__ __launch_bounds__(256) void gemm128(
    const u16* __restrict__ A, const u16* __restrict__ Bt, int mode,
    const float* __restrict__ bq, const float* __restrict__ bv,
    u16* __restrict__ qkvb, float* __restrict__ kout, float* __restrict__ vout,
    u16* __restrict__ vbT,
    const float* __restrict__ bo, float* __restrict__ outp)
{
    __shared__ u16 As[128][32];   // unpadded: required by global_load_lds lane-order dest
    __shared__ u16 Bs[128][32];
    const int m0 = blockIdx.y * 128;
    const int n0 = blockIdx.x * 128;
    const int tid = threadIdx.x;
    const int wave = tid >> 6, lane = tid & 63;
    const int wy = wave >> 1, wx = wave & 1;       // 2x2 waves, 64x64 each
    const int lrow = lane & 15, lquad = lane >> 4;

    floatx4 acc[4][4];
    #pragma unroll
    for (int i = 0; i < 4; ++i)
        #pragma unroll
        for (int j = 0; j < 4; ++j)
            acc[i][j] = (floatx4){0.f, 0.f, 0.f, 0.f};

    // staging: chunk tid covers (row=tid>>2, kseg=tid&3); LDS offset = tid*16 B
    const u16* agp0 = A + (size_t)(m0 + (tid >> 2)) * 1024 + (tid & 3) * 8;
    const u16* agp1 = agp0 + (size_t)64 * 1024;
    const u16* bgp0 = Bt + (size_t)(n0 + (tid >> 2)) * 1024 + (tid & 3) * 8;
    const u16* bgp1 = bgp0 + (size_t)64 * 1024;
    char* lA0 = (char*)&As[0][0] + wave * 1024;
    char* lA1 = lA0 + 4096;
    char* lB0 = (char*)&Bs[0][0] + wave * 1024;
    char* lB1 = lB0 + 4096;

    for (int k0 = 0; k0 < 1024; k0 += 32) {
        __syncthreads();               // previous tile's fragment reads done
        gload16(agp0 + k0, lA0);
        gload16(agp1 + k0, lA1);
        gload16(bgp0 + k0, lB0);
        gload16(bgp1 + k0, lB1);
        __syncthreads();               // vmcnt(0) drain before reads
        short8 af[4], bfr[4];
        #pragma unroll
        for (int i = 0; i < 4; ++i)
            af[i] = *(const short8*)&As[wy * 64 + i * 16 + lrow][lquad * 8];
        #pragma unroll
        for (int j = 0; j < 4; ++j)
            bfr[j] = *(const short8*)&Bs[wx * 64 + j * 16 + lrow][lquad * 8];
        #pragma unroll
        for (int i = 0; i < 4; ++i)
            #pragma unroll
            for (int j = 0; j < 4; ++j)
                acc[i][j] = __builtin_amdgcn_mfma_f32_16x16x32_bf16(af[i], bfr[j], acc[i][j], 0, 0, 0);
    }

    const int sec = (mode == 0) ? (n0 >> 10) : 3;   // 0=q 1=k 2=v 3=out
    #pragma unroll
    for (int j = 0; j < 4; ++j) {
        const int col = n0 + wx * 64 + j * 16 + lrow;
        float bb;
        if (mode == 1) bb = bo[col];
        else bb = (sec == 0) ? bq[col] : (sec == 2 ? bv[col - 2048] : 0.f);
        #pragma unroll
        for (int i = 0; i < 4; ++i) {
            #pragma unroll
            for (int r = 0; r < 4; ++r) {
                const int row = m0 + wy * 64 + i * 16 + lquad * 4 + r;
                const float v = acc[i][j][r] + bb;
                if (mode == 1) {
                    outp[(size_t)row * 1024 + col] = v;
                } else if (sec == 0) {
                    qkvb[(size_t)row * 3072 + col] = f2bf(v);
                } else if (sec == 1) {
                    qkvb[(size_t)row * 3072 + col] = f2bf(v);
                    kout[(size_t)row * 1024 + col - 1024] = v;
                } else {
                    vout[(size_t)row * 1024 + col - 2048] = v;
                    const int bidx = row / 448, tt = row - bidx * 448;
                    vbT[((size_t)bidx * 1024 + (col - 2048)) * 448 + tt] = f2bf(v);
                }
            }
        }
    }
}

// ---------------- flash attention, bf16 MFMA ----------------
// Block: 64 queries (4 waves x 16) of one (b,h). K tiles from qkvb, V tiles from vbT.
__global__ __launch_bounds__(256) void flash_attn(
    const u16* __restrict__ QKVb,   // [M][3072]
    const u16* __restrict__ VbT,    // [B*H][64][448]
    u16* __restrict__ Ob)           // [M][1024]
{
    __shared__ u16 Qs[64][72];
    __shared__ u16 Ks[64][72];      // [key][d]
    __shared__ u16 Vt[64][72];      // [d][key]
    __shared__ u16 Pt[4][16][72];
    const int qt = blockIdx.x;      // 0..6
    const int bh = blockIdx.y;      // 0..127
    const int h = bh & (H - 1), b = bh >> 4;
    const int tid = threadIdx.x, wave = tid >> 6, lane = tid & 63;
    const int lrow = lane & 15, lquad = lane >> 4;
    const int q0 = qt * 64;

    const u16* qbase = QKVb + (size_t)b * T * 3072 + (size_t)h * DH;
    const u16* kbase = qbase + 1024;
    const u16* vtb   = VbT + (size_t)bh * DH * T;

    {
        const int s = tid * 2;
        short8 v0 = *(const short8*)(qbase + (size_t)(q0 + (s >> 3)) * 3072 + (s & 7) * 8);
        short8 v1 = *(const short8*)(qbase + (size_t)(q0 + ((s + 1) >> 3)) * 3072 + ((s + 1) & 7) * 8);
        *(short8*)&Qs[s >> 3][(s & 7) * 8] = v0;
        *(short8*)&Qs[(s + 1) >> 3][((s + 1) & 7) * 8] = v1;
    }
    __syncthreads();
    short8 aq0 = *(const short8*)&Qs[wave * 16 + lrow][lquad * 8];
    short8 aq1 = *(const short8*)&Qs[wave * 16 + lrow][32 + lquad * 8];

    float m_i[4], l_i[4];
    floatx4 oacc[4];
    #pragma unroll
    for (int r = 0; r < 4; ++r) { m_i[r] = -INFINITY; l_i[r] = 0.f; }
    #pragma unroll
    for (int n = 0; n < 4; ++n) oacc[n] = (floatx4){0.f, 0.f, 0.f, 0.f};

    const float SC = 0.125f * 1.44269504088896340736f;
    const int nkt = qt + 1;

    for (int kt = 0; kt < nkt; ++kt) {
        const int k0 = kt * 64;
        {
            const int s = tid * 2;
            const int r0 = s >> 3, o0 = (s & 7) * 8;
            const int r1 = (s + 1) >> 3, o1 = ((s + 1) & 7) * 8;
            short8 kv0 = *(const short8*)(kbase + (size_t)(k0 + r0) * 3072 + o0);
            short8 kv1 = *(const short8*)(kbase + (size_t)(k0 + r1) * 3072 + o1);
            short8 vv0 = *(const short8*)(vtb + (size_t)r0 * T + k0 + o0);   // [d=r0][key]
            short8 vv1 = *(const short8*)(vtb + (size_t)r1 * T + k0 + o1);
            __syncthreads();
            *(short8*)&Ks[r0][o0] = kv0;
            *(short8*)&Ks[r1][o1] = kv1;
            *(short8*)&Vt[r0][o0] = vv0;
            *(short8*)&Vt[r1][o1] = vv1;
        }
        __syncthreads();

        floatx4 s4[4];
        #pragma unroll
        for (int sub = 0; sub < 4; ++sub) {
            short8 bk0 = *(const short8*)&Ks[sub * 16 + lrow][lquad * 8];
            short8 bk1 = *(const short8*)&Ks[sub * 16 + lrow][32 + lquad * 8];
            floatx4 z = (floatx4){0.f, 0.f, 0.f, 0.f};
            z = __builtin_amdgcn_mfma_f32_16x16x32_bf16(aq0, bk0, z, 0, 0, 0);
            z = __builtin_amdgcn_mfma_f32_16x16x32_bf16(aq1, bk1, z, 0, 0, 0);
            s4[sub] = z;
        }

        float p[4][4];
        #pragma unroll
        for (int r = 0; r < 4; ++r) {
            const int qg = q0 + wave * 16 + lquad * 4 + r;
            float sv[4];
            float mx = -INFINITY;
            #pragma unroll
            for (int sub = 0; sub < 4; ++sub) {
                const int kk = k0 + sub * 16 + lrow;
                float v = s4[sub][r] * SC;
                v = (kk <= qg) ? v : -INFINITY;
                sv[sub] = v;
                mx = fmaxf(mx, v);
            }
            mx = fmaxf(mx, __shfl_xor(mx, 1));
            mx = fmaxf(mx, __shfl_xor(mx, 2));
            mx = fmaxf(mx, __shfl_xor(mx, 4));
            mx = fmaxf(mx, __shfl_xor(mx, 8));
            const float mnew = fmaxf(m_i[r], mx);
            const float alpha = exp2f(m_i[r] - mnew);
            float ls = 0.f;
            #pragma unroll
            for (int sub = 0; sub < 4; ++sub) {
                const float pv = exp2f(sv[sub] - mnew);
                p[sub][r] = pv;
                ls += pv;
            }
            ls += __shfl_xor(ls, 1);
            ls += __shfl_xor(ls, 2);
            ls += __shfl_xor(ls, 4);
            ls += __shfl_xor(ls, 8);
            l_i[r] = l_i[r] * alpha + ls;
            m_i[r] = mnew;
            #pragma unroll
            for (int n = 0; n < 4; ++n) oacc[n][r] *= alpha;
        }

        #pragma unroll
        for (int sub = 0; sub < 4; ++sub)
            #pragma unroll
            for (int r = 0; r < 4; ++r)
                Pt[wave][lquad * 4 + r][sub * 16 + lrow] = f2bf(p[sub][r]);
        __syncthreads();
        short8 ap0 = *(const short8*)&Pt[wave][lrow][lquad * 8];
        short8 ap1 = *(const short8*)&Pt[wave][lrow][32 + lquad * 8];

        #pragma unroll
        for (int n = 0; n < 4; ++n) {
            short8 bv0 = *(const short8*)&Vt[n * 16 + lrow][lquad * 8];
            short8 bv1 = *(const short8*)&Vt[n * 16 + lrow][32 + lquad * 8];
            oacc[n] = __builtin_amdgcn_mfma_f32_16x16x32_bf16(ap0, bv0, oacc[n], 0, 0, 0);
            oacc[n] = __builtin_amdgcn_mfma_f32_16x16x32_bf16(ap1, bv1, oacc[n], 0, 0, 0);
        }
    }

    #pragma unroll
    for (int r = 0; r < 4; ++r) {
        const float inv = 1.f / l_i[r];
        const int qg = q0 + wave * 16 + lquad * 4 + r;
        u16* orow = Ob + ((size_t)b * T + qg) * D + (size_t)h * DH;
        #pragma unroll
        for (int n = 0; n < 4; ++n)
            orow[n * 16 + lrow] = f2bf(oacc[n][r] * inv);
    }
}

extern "C" void kernel_launch(void* const* d_in, const int* in_sizes, int n_in,
                              void* d_out, int out_size, void* d_ws, size_t ws_size,
                              hipStream_t stream) {
    const float* x  = (const float*)d_in[0];
    // d_in[1]=k_cache, d_in[2]=v_cache fully overwritten (T_new==T); d_in[3]=mask pure causal
    const float* Wq = (const float*)d_in[4];
    const float* bq = (const float*)d_in[5];
    const float* Wk = (const float*)d_in[6];
    const float* Wv = (const float*)d_in[7];
    const float* bv = (const float*)d_in[8];
    const float* Wo = (const float*)d_in[9];
    const float* bo = (const float*)d_in[10];

    float* out  = (float*)d_out;                  // [M,D]
    float* kout = out + (size_t)M * D;            // k_cache = x@Wk
    float* vout = out + 2 * (size_t)M * D;        // v_cache = x@Wv+bv

    u16* xb   = (u16*)d_ws;                       // [M][1024] bf16 x
    u16* wt   = xb   + (size_t)M * D;             // [4][1024][1024] bf16 W^T (q,k,v,o)
    u16* qkvb = wt   + (size_t)4 * D * D;         // [M][3072] bf16 q|k|v
    u16* vbT  = qkvb + (size_t)M * 3 * D;         // [B*H][64][448] bf16 v^T
    u16* ab   = vbT  + (size_t)M * D;             // [M][1024] bf16 attn out

    xconv<<<M * D / 1024, 256, 0, stream>>>(x, xb);
    wconv4<<<dim3(16, 16, 4), 256, 0, stream>>>(Wq, Wk, Wv, Wo, wt);

    // fused QKV: N=3072
    gemm128<<<dim3(24, 28), 256, 0, stream>>>(xb, wt, 0, bq, bv,
                                              qkvb, kout, vout, vbT, nullptr, nullptr);

    flash_attn<<<dim3(7, 128), 256, 0, stream>>>(qkvb, vbT, ab);

    // output projection: N=1024
    gemm128<<<dim3(8, 28), 256, 0, stream>>>(ab, wt + (size_t)3 * D * D, 1, nullptr, nullptr,
                                             nullptr, nullptr, nullptr, nullptr, bo, out);
}